// Round 7
// baseline (326.549 us; speedup 1.0000x reference)
//
#include <hip/hip_runtime.h>
#include <math.h>

// Problem constants (B=8, S=2048, D=512)
#define B_ 8
#define S_ 2048
#define D_ 512
#define KTOP 204                      // int(2048*0.1)
#define QK_SCALE 0.044194173824159216f // 1/sqrt(512)

typedef short bfrag8 __attribute__((ext_vector_type(8)));  // 8 bf16 (4 VGPRs)
typedef float facc4 __attribute__((ext_vector_type(4)));   // MFMA accumulator

// ---------- helpers ----------
__device__ __forceinline__ unsigned short f2bf(float f) {
  unsigned u = __float_as_uint(f);
  u += 0x7FFFu + ((u >> 16) & 1);   // RNE
  return (unsigned short)(u >> 16);
}

// order-preserving map: descending float order == descending uint order
__device__ __forceinline__ unsigned fkey(float f) {
  unsigned b = __float_as_uint(f);
  return (b & 0x80000000u) ? ~b : (b | 0x80000000u);
}
__device__ __forceinline__ float keyfloat(unsigned k) {
  unsigned b = (k & 0x80000000u) ? (k & 0x7FFFFFFFu) : ~k;
  return __uint_as_float(b);
}

__device__ __forceinline__ void load16(const unsigned short* g, unsigned short* l) {
  __builtin_amdgcn_global_load_lds(
      (const __attribute__((address_space(1))) void*)g,
      (__attribute__((address_space(3))) void*)l, 16, 0, 0);
}

// ---------- fused prep: fp32->bf16 cvt of Q,K + V transpose, one launch ----------
// grid: [0,8192) cvt Q; [8192,16384) cvt K; [16384,24576) transpose V.
__global__ __launch_bounds__(256) void prep(const float* __restrict__ Q,
                                            const float* __restrict__ K,
                                            const float* __restrict__ V,
                                            unsigned short* __restrict__ Qb,
                                            unsigned short* __restrict__ Kb,
                                            unsigned short* __restrict__ VT) {
  __shared__ float tile[32][33];
  const unsigned j = blockIdx.x;
  if (j < 16384u) {
    const float* in = (j < 8192u) ? Q : K;
    unsigned short* out = (j < 8192u) ? Qb : Kb;
    int i = (int)(((j & 8191u) * 256u + threadIdx.x) * 4u);
    float4 v = *(const float4*)(in + i);
    ushort4 o;
    o.x = f2bf(v.x); o.y = f2bf(v.y); o.z = f2bf(v.z); o.w = f2bf(v.w);
    *(ushort4*)(out + i) = o;
  } else {
    const unsigned t = j - 16384u;
    const int d0 = (int)(t & 15u) * 32, k0 = (int)((t >> 4) & 63u) * 32;
    const int b = (int)(t >> 10);
    const float* Vb = V + (size_t)b * S_ * D_;
    unsigned short* VTb = VT + (size_t)b * D_ * S_;
    int c = threadIdx.x & 31, r = threadIdx.x >> 5;
#pragma unroll
    for (int rr = 0; rr < 32; rr += 8)
      tile[r + rr][c] = Vb[(size_t)(k0 + r + rr) * D_ + d0 + c];
    __syncthreads();
#pragma unroll
    for (int rr = 0; rr < 32; rr += 8)
      VTb[(size_t)(d0 + r + rr) * S_ + k0 + c] = f2bf(tile[c][r + rr]);
  }
}

// ---------- batched BT-layout MFMA GEMM (verbatim R6) ----------
// gemm1 variant: grid (16,16,8); bz = j&7 pins batch to XCD (Qb[b]+Kb[b] = 4 MB L2)
__global__ __launch_bounds__(256) void gemm_qk(
    const unsigned short* __restrict__ A, int lda, long long astr,
    const unsigned short* __restrict__ Bm, int ldb, long long bstr,
    float* __restrict__ C, int ldc, long long cstr,
    int kdim, float scale) {
  const unsigned j = blockIdx.x + 16u * blockIdx.y + 256u * blockIdx.z;
  const unsigned bz = j & 7u;           // batch == XCD residue
  const unsigned q = j >> 3;            // [0,256)
  const unsigned by = q & 15u;          // m-tile
  const unsigned bx = q >> 4;           // n-tile [0,16)

  __shared__ unsigned short smA[128 * 32];
  __shared__ unsigned short smB[128 * 32];
  const int tid = threadIdx.x;
  const int wave = tid >> 6, lane = tid & 63;
  const int quad = lane >> 4, l15 = lane & 15;
  const unsigned short* Ab = A + (long long)bz * astr + (size_t)(by * 128) * lda;
  const unsigned short* Bb = Bm + (long long)bz * bstr + (size_t)(bx * 128) * ldb;
  const int srow = tid >> 2;          // staging row 0..63
  const int scol = (tid & 3) * 8;     // staging col (elements)
  unsigned short* lA0 = smA + wave * 512;
  unsigned short* lA1 = smA + 2048 + wave * 512;
  unsigned short* lB0 = smB + wave * 512;
  unsigned short* lB1 = smB + 2048 + wave * 512;
  const int mrow = 64 * (wave >> 1);
  const int nrow = 64 * (wave & 1);

  facc4 acc[4][4];
  const facc4 fzero = {0.f, 0.f, 0.f, 0.f};
#pragma unroll
  for (int i = 0; i < 4; ++i)
#pragma unroll
    for (int j2 = 0; j2 < 4; ++j2) acc[i][j2] = fzero;

  for (int k0 = 0; k0 < kdim; k0 += 32) {
    __syncthreads();
    load16(Ab + (size_t)srow * lda + k0 + scol, lA0);
    load16(Ab + (size_t)(srow + 64) * lda + k0 + scol, lA1);
    load16(Bb + (size_t)srow * ldb + k0 + scol, lB0);
    load16(Bb + (size_t)(srow + 64) * ldb + k0 + scol, lB1);
    __syncthreads();
    bfrag8 af[4], bq[4];
#pragma unroll
    for (int i = 0; i < 4; ++i)
      af[i] = *(const bfrag8*)(smA + (mrow + 16 * i + l15) * 32 + quad * 8);
#pragma unroll
    for (int j2 = 0; j2 < 4; ++j2)
      bq[j2] = *(const bfrag8*)(smB + (nrow + 16 * j2 + l15) * 32 + quad * 8);
#pragma unroll
    for (int i = 0; i < 4; ++i)
#pragma unroll
      for (int j2 = 0; j2 < 4; ++j2)
        acc[i][j2] = __builtin_amdgcn_mfma_f32_16x16x32_bf16(af[i], bq[j2], acc[i][j2], 0, 0, 0);
  }

  float* Cb = C + (long long)bz * cstr;
  const int mg = by * 128 + mrow;
  const int ng = bx * 128 + nrow;
#pragma unroll
  for (int i = 0; i < 4; ++i)
#pragma unroll
    for (int j2 = 0; j2 < 4; ++j2)
#pragma unroll
      for (int r = 0; r < 4; ++r)
        Cb[(size_t)(mg + 16 * i + quad * 4 + r) * ldc + ng + 16 * j2 + l15] = acc[i][j2][r] * scale;
}

// gemm2 variant: grid (4,16,8); bz = j&7 (VT[b] 2 MB in XCD L2); bx fastest so the
// 4 n-blocks sharing one 512 KB attn A-tile run back-to-back on the same XCD.
__global__ __launch_bounds__(256) void gemm_pv(
    const unsigned short* __restrict__ A, int lda, long long astr,
    const unsigned short* __restrict__ Bm, int ldb, long long bstr,
    float* __restrict__ C, int ldc, long long cstr,
    int kdim, float scale) {
  const unsigned j = blockIdx.x + 4u * blockIdx.y + 64u * blockIdx.z;
  const unsigned bz = j & 7u;           // batch == XCD residue
  const unsigned q = j >> 3;            // [0,64)
  const unsigned bx = q & 3u;           // n-tile (fastest)
  const unsigned by = q >> 2;           // m-tile [0,16)

  __shared__ unsigned short smA[128 * 32];
  __shared__ unsigned short smB[128 * 32];
  const int tid = threadIdx.x;
  const int wave = tid >> 6, lane = tid & 63;
  const int quad = lane >> 4, l15 = lane & 15;
  const unsigned short* Ab = A + (long long)bz * astr + (size_t)(by * 128) * lda;
  const unsigned short* Bb = Bm + (long long)bz * bstr + (size_t)(bx * 128) * ldb;
  const int srow = tid >> 2;          // staging row 0..63
  const int scol = (tid & 3) * 8;     // staging col (elements)
  unsigned short* lA0 = smA + wave * 512;
  unsigned short* lA1 = smA + 2048 + wave * 512;
  unsigned short* lB0 = smB + wave * 512;
  unsigned short* lB1 = smB + 2048 + wave * 512;
  const int mrow = 64 * (wave >> 1);
  const int nrow = 64 * (wave & 1);

  facc4 acc[4][4];
  const facc4 fzero = {0.f, 0.f, 0.f, 0.f};
#pragma unroll
  for (int i = 0; i < 4; ++i)
#pragma unroll
    for (int j2 = 0; j2 < 4; ++j2) acc[i][j2] = fzero;

  for (int k0 = 0; k0 < kdim; k0 += 32) {
    __syncthreads();
    load16(Ab + (size_t)srow * lda + k0 + scol, lA0);
    load16(Ab + (size_t)(srow + 64) * lda + k0 + scol, lA1);
    load16(Bb + (size_t)srow * ldb + k0 + scol, lB0);
    load16(Bb + (size_t)(srow + 64) * ldb + k0 + scol, lB1);
    __syncthreads();
    bfrag8 af[4], bq[4];
#pragma unroll
    for (int i = 0; i < 4; ++i)
      af[i] = *(const bfrag8*)(smA + (mrow + 16 * i + l15) * 32 + quad * 8);
#pragma unroll
    for (int j2 = 0; j2 < 4; ++j2)
      bq[j2] = *(const bfrag8*)(smB + (nrow + 16 * j2 + l15) * 32 + quad * 8);
#pragma unroll
    for (int i = 0; i < 4; ++i)
#pragma unroll
      for (int j2 = 0; j2 < 4; ++j2)
        acc[i][j2] = __builtin_amdgcn_mfma_f32_16x16x32_bf16(af[i], bq[j2], acc[i][j2], 0, 0, 0);
  }

  float* Cb = C + (long long)bz * cstr;
  const int mg = by * 128 + mrow;
  const int ng = bx * 128 + nrow;
#pragma unroll
  for (int i = 0; i < 4; ++i)
#pragma unroll
    for (int j2 = 0; j2 < 4; ++j2)
#pragma unroll
      for (int r = 0; r < 4; ++r)
        Cb[(size_t)(mg + 16 * i + quad * 4 + r) * ldc + ng + 16 * j2 + l15] = acc[i][j2][r] * scale;
}

// ---------- per-row exact top-204 + softmax-of-sparse; one WAVE per row ----------
// R2 selection semantics EXACTLY (bit-identical output). Changes vs R2, all
// integer/bit-equivalent: (1) 2 sub-histogram copies per wave (one per 32-lane
// half, stride 272 words for bank skew) merged by integer add at pick time;
// (2) score floats kept in registers (fv[]) so the weight pass uses fv[i]
// directly (keyfloat(fkey(x))==x bitwise); (3) pack loop selects precomputed
// bf16 for w==base / w==eqw (f2bf of bitwise-equal floats is identical).
__global__ __launch_bounds__(256) void topk_softmax(float* __restrict__ scores) {
  __shared__ unsigned binsAll[4][544];   // per wave: 2 copies of 256 bins, stride 272
  const int tid = threadIdx.x;
  const int wave = tid >> 6, lane = tid & 63;
  const long long row = (long long)blockIdx.x * 4 + wave;
  float* srow = scores + row * 2048;
  unsigned* bins = binsAll[wave];
  const unsigned gb = (unsigned)(lane >> 5) * 272u;   // sub-histogram base

  float fv[32];
  unsigned k[32];
#pragma unroll
  for (int c = 0; c < 4; ++c) {
    float4 a = *(const float4*)(srow + c * 512 + lane * 8);
    float4 b = *(const float4*)(srow + c * 512 + lane * 8 + 4);
    fv[c * 8 + 0] = a.x; fv[c * 8 + 1] = a.y; fv[c * 8 + 2] = a.z; fv[c * 8 + 3] = a.w;
    fv[c * 8 + 4] = b.x; fv[c * 8 + 5] = b.y; fv[c * 8 + 6] = b.z; fv[c * 8 + 7] = b.w;
  }
#pragma unroll
  for (int i = 0; i < 32; ++i) k[i] = fkey(fv[i]);

  // row max (for softmax shift m = max(max_score, 0))
  unsigned kmax = 0;
#pragma unroll
  for (int i = 0; i < 32; ++i) kmax = max(kmax, k[i]);
#pragma unroll
  for (int off = 1; off < 64; off <<= 1)
    kmax = max(kmax, (unsigned)__shfl_xor((int)kmax, off));
  const float m = fmaxf(keyfloat(kmax), 0.f);

  // 4-pass radix select (MSB->LSB) for the KTOP-th largest key
  unsigned prefix = 0, mmask = 0, krem = KTOP;
  for (int shift = 24; shift >= 0; shift -= 8) {
    uint4 z; z.x = z.y = z.z = z.w = 0;
    *(uint4*)(bins + lane * 8) = z;
    *(uint4*)(bins + lane * 8 + 4) = z;
    if (lane < 8) *(uint4*)(bins + 512 + lane * 4) = z;
#pragma unroll
    for (int i = 0; i < 32; ++i)
      if ((k[i] & mmask) == prefix)
        atomicAdd(&bins[gb + ((k[i] >> shift) & 255u)], 1u);
    uint4 b0 = *(const uint4*)(bins + lane * 4);
    uint4 b1 = *(const uint4*)(bins + 272 + lane * 4);
    uint4 b;
    b.x = b0.x + b1.x; b.y = b0.y + b1.y; b.z = b0.z + b1.z; b.w = b0.w + b1.w;
    unsigned s = b.x + b.y + b.z + b.w;
    // inclusive suffix scan of s over lanes (sum over lanes >= this lane)
    unsigned t = s;
#pragma unroll
    for (int off = 1; off < 64; off <<= 1) {
      unsigned u = (unsigned)__shfl_down((int)t, off);
      t += (lane + off < 64) ? u : 0u;
    }
    const unsigned texcl = t - s;           // suffix over lanes > lane
    const unsigned c3 = texcl + b.w;        // count(digit >= lane*4+3)
    const unsigned c2 = c3 + b.z;
    const unsigned c1 = c2 + b.y;
    const unsigned c0 = c1 + b.x;
    unsigned pack = 0;                      // nonzero in exactly one lane
    if (c0 >= krem && c1 < krem)   pack = ((krem - c1) << 8) | (lane * 4 + 0);
    if (c1 >= krem && c2 < krem)   pack = ((krem - c2) << 8) | (lane * 4 + 1);
    if (c2 >= krem && c3 < krem)   pack = ((krem - c3) << 8) | (lane * 4 + 2);
    if (c3 >= krem && texcl < krem) pack = ((krem - texcl) << 8) | (lane * 4 + 3);
#pragma unroll
    for (int off = 1; off < 64; off <<= 1)
      pack |= (unsigned)__shfl_xor((int)pack, off);
    prefix |= (pack & 255u) << shift;
    krem = pack >> 8;                       // >=1 by construction
    mmask |= 0xFFu << shift;
  }
  const unsigned tkey = prefix;

  // tie-break: accept the krem lowest-index elements with key == tkey.
  // cut = global index of the last accepted tie.
  unsigned cut;
  {
    unsigned tiem = 0;
#pragma unroll
    for (int i = 0; i < 32; ++i)
      if (k[i] == tkey) tiem |= 1u << i;
    unsigned need = krem;
    for (;;) {
      unsigned myidx = 0xFFFFFFFFu;
      if (tiem) {
        int i = __ffs((int)tiem) - 1;       // lowest i = smallest global idx in lane
        myidx = ((unsigned)(i >> 3)) * 512u + (unsigned)lane * 8u + (unsigned)(i & 7);
      }
      unsigned minidx = myidx;
#pragma unroll
      for (int off = 1; off < 64; off <<= 1)
        minidx = min(minidx, (unsigned)__shfl_xor((int)minidx, off));
      if (--need == 0 || minidx == 0xFFFFFFFFu) { cut = minidx; break; }
      if (myidx == minidx) tiem &= tiem - 1; // consume in owning lane
    }
  }

  // weights: exp(s-m) if selected, exp(-m) otherwise; Z = sum of all weights
  const float eqw = __expf(keyfloat(tkey) - m);
  const float base = __expf(-m);
  float zsum = 0.f;
#pragma unroll
  for (int i = 0; i < 32; ++i) {
    const unsigned key = k[i];
    const unsigned idx = ((unsigned)(i >> 3)) * 512u + (unsigned)lane * 8u + (unsigned)(i & 7);
    float w;
    if (key > tkey) w = __expf(fv[i] - m);  // fv[i] bitwise == keyfloat(key)
    else w = (key == tkey && idx <= cut) ? eqw : base;
    zsum += w;
    k[i] = __float_as_uint(w);              // stash unnormalized weight
  }
#pragma unroll
  for (int off = 1; off < 64; off <<= 1) zsum += __shfl_xor(zsum, off);
  const float invZ = 1.f / zsum;

  // attn row (bf16) reuses the front 4KB of this row's 8KB score slot
  const unsigned ubase = __float_as_uint(base);
  const unsigned ueqw = __float_as_uint(eqw);
  const unsigned short bf_base = f2bf(base * invZ);
  const unsigned short bf_eq = f2bf(eqw * invZ);
  unsigned short* arow = (unsigned short*)scores + row * 4096;
#pragma unroll
  for (int c = 0; c < 4; ++c) {
    union { unsigned short u[8]; int4 v4; } pk;
#pragma unroll
    for (int j = 0; j < 8; ++j) {
      const unsigned wb = k[c * 8 + j];
      pk.u[j] = (wb == ubase) ? bf_base
              : (wb == ueqw)  ? bf_eq
              : f2bf(__uint_as_float(wb) * invZ);
    }
    *(int4*)(arow + c * 512 + lane * 8) = pk.v4;
  }
}

// ---------- launch ----------
// ws layout (bytes): Qb[0,16MB) Kb[16,32MB) VT[32,48MB) scores/attn[48,176MB)
extern "C" void kernel_launch(void* const* d_in, const int* in_sizes, int n_in,
                              void* d_out, int out_size, void* d_ws, size_t ws_size,
                              hipStream_t stream) {
  const float* Q = (const float*)d_in[0];
  const float* K = (const float*)d_in[1];
  const float* V = (const float*)d_in[2];
  float* out = (float*)d_out;
  char* ws = (char*)d_ws;
  unsigned short* Qb = (unsigned short*)(ws);
  unsigned short* Kb = (unsigned short*)(ws + ((size_t)16 << 20));
  unsigned short* VT = (unsigned short*)(ws + ((size_t)32 << 20));
  float* scores = (float*)(ws + ((size_t)48 << 20));

  prep<<<24576, 256, 0, stream>>>(Q, K, V, Qb, Kb, VT);
  // scores[b][q][k] = sum_d Q[q][d]*K[k][d] * scale ; score row pitch = 2048 f32
  gemm_qk<<<dim3(S_ / 128, S_ / 128, B_), 256, 0, stream>>>(
      Qb, D_, (long long)S_ * D_, Kb, D_, (long long)S_ * D_,
      scores, S_, (long long)S_ * S_, D_, QK_SCALE);
  topk_softmax<<<B_ * S_ / 4, 256, 0, stream>>>(scores);
  // out[b][q][d] = sum_k attn[q][k]*VT[d][k] ; attn row pitch = 4096 bf16 (8KB slots)
  gemm_pv<<<dim3(D_ / 128, S_ / 128, B_), 256, 0, stream>>>(
      (const unsigned short*)scores, 4096, (long long)S_ * 4096,
      VT, S_, (long long)D_ * S_, out, D_, (long long)S_ * D_, S_, 1.0f);
}